// Round 1
// baseline (11498.949 us; speedup 1.0000x reference)
//
#include <hip/hip_runtime.h>
#include <hip/hip_bf16.h>
#include <math.h>

// Problem constants (reference: B=8, H=W=512)
#define Bsz    8
#define Wdim   512
#define HWv    (512 * 512)       // 262144 = 2^18
#define LOG2HW 18
#define NIMG   16                // {bg(0..7), fg(8..15)}

// ws layout (int32 units):
//   [0, NIMG*HWv)            labels
//   [NIMG*HWv, 2*NIMG*HWv)   areas
//   [2*NIMG*HWv, +16)        per-image max area
//   then (8-byte aligned):   double sums[2]; int counts[2]
// total ~33.6 MB — requires ws_size >= 33,554,520 bytes.

// ---------------- union-find (all writes via atomicMin: parents only ever
// decrease, links always point to smaller index => final root == component min;
// lock-free correct under concurrency) ----------------
__device__ __forceinline__ int uf_find(int* L, int x) {
  int p = L[x];
  while (p != x) {
    int gp = L[p];
    if (gp != p) atomicMin(&L[x], gp);  // grandparent compression (monotone)
    x = gp;
    p = L[x];
  }
  return x;
}

__device__ __forceinline__ void uf_union(int* L, int a, int b) {
  a = uf_find(L, a);
  b = uf_find(L, b);
  while (a != b) {
    if (a < b) { int t = a; a = b; b = t; }  // ensure a > b
    int old = atomicMin(&L[a], b);
    if (old == a) return;  // linked a -> b
    a = old;               // a's parent was already lowered; keep merging
  }
}

// ---------------- kernels ----------------
__global__ void k_init(const float* __restrict__ cams, int* __restrict__ labels,
                       int* __restrict__ areas, int* __restrict__ maxa,
                       double* __restrict__ sums, int* __restrict__ counts) {
  int idx = blockIdx.x * blockDim.x + threadIdx.x;
  if (idx < NIMG * HWv) {
    int img = idx >> LOG2HW;       // 0..15
    int p   = idx & (HWv - 1);
    int b   = img & 7;
    float c = cams[(b << LOG2HW) + p];
    bool m = (img & 8) ? (c > 0.6f) : (c >= 0.2f);  // fg : bg
    labels[idx] = m ? p : -1;
    areas[idx]  = 0;
  }
  if (idx < NIMG) maxa[idx] = 0;
  if (idx < 2) { sums[idx] = 0.0; counts[idx] = 0; }
}

__global__ void k_merge(int* __restrict__ labels) {
  int idx = blockIdx.x * blockDim.x + threadIdx.x;
  if (idx >= NIMG * HWv) return;
  if (labels[idx] < 0) return;               // off-mask (stable: never unioned)
  int img = idx >> LOG2HW;
  int p   = idx & (HWv - 1);
  int* L  = labels + (img << LOG2HW);
  int x   = p & (Wdim - 1);
  if (x < Wdim - 1 && L[p + 1] >= 0)    uf_union(L, p, p + 1);     // east
  if (p < HWv - Wdim && L[p + Wdim] >= 0) uf_union(L, p, p + Wdim); // south
}

__global__ void k_flatten(int* __restrict__ labels, int* __restrict__ areas) {
  int idx = blockIdx.x * blockDim.x + threadIdx.x;
  if (idx >= NIMG * HWv) return;
  if (labels[idx] < 0) return;
  int img  = idx >> LOG2HW;
  int base = img << LOG2HW;
  int root = uf_find(labels + base, idx - base);
  atomicMin(&labels[idx], root);   // root == component min => label := root
  atomicAdd(&areas[base + root], 1);
}

__global__ void k_max(const int* __restrict__ areas, int* __restrict__ maxa) {
  int idx = blockIdx.x * blockDim.x + threadIdx.x;
  if (idx >= NIMG * HWv) return;
  int a = areas[idx];
  if (a > 0) atomicMax(&maxa[idx >> LOG2HW], a);
}

__global__ void k_ce(const float* __restrict__ preds, const int* __restrict__ labels,
                     const int* __restrict__ areas, const int* __restrict__ maxa,
                     double* __restrict__ sums, int* __restrict__ counts) {
  int idx = blockIdx.x * blockDim.x + threadIdx.x;  // over B*HW
  float s_fg = 0.f, s_bg = 0.f;
  int c_fg = 0, c_bg = 0;
  if (idx < Bsz * HWv) {
    int b = idx >> LOG2HW;
    int p = idx & (HWv - 1);
    // bg image = b  (labels index == idx); fg image = 8 + b
    int rb = labels[idx];
    bool keep_bg = false;
    if (rb >= 0) {
      int a = areas[(b << LOG2HW) + rb];
      keep_bg = (2 * a > maxa[b]);           // == (a > 0.5*max) for ints
    }
    int rf = labels[(8 << LOG2HW) + idx];
    bool keep_fg = false;
    if (rf >= 0) {
      int a = areas[((8 + b) << LOG2HW) + rf];
      keep_fg = (2 * a > maxa[8 + b]);
    }
    bool v_fg = keep_fg;     // fg_t == 1   where kept, else ignore(255)
    bool v_bg = !keep_bg;    // bg_t == 255 where kept, else class 0
    c_fg = v_fg ? 1 : 0;
    c_bg = v_bg ? 1 : 0;
    if (v_fg || v_bg) {
      #pragma unroll
      for (int i = 0; i < 3; i++) {
        const float* pb = preds + (size_t)(((i * Bsz + b) * 2) << LOG2HW);
        float l0 = pb[p];
        float l1 = pb[HWv + p];
        float m  = fmaxf(l0, l1);
        float lse = m + logf(expf(l0 - m) + expf(l1 - m));
        if (v_fg) s_fg += lse - l1;   // -log_softmax[class 1]
        if (v_bg) s_bg += lse - l0;   // -log_softmax[class 0]
      }
    }
  }
  // block reduction: wave64 shuffle -> LDS -> 4 atomics/block
  #pragma unroll
  for (int off = 32; off > 0; off >>= 1) {
    s_fg += __shfl_down(s_fg, off);
    s_bg += __shfl_down(s_bg, off);
    c_fg += __shfl_down(c_fg, off);
    c_bg += __shfl_down(c_bg, off);
  }
  __shared__ float lsf[4], lsb[4];
  __shared__ int   lcf[4], lcb[4];
  int wave = threadIdx.x >> 6;
  if ((threadIdx.x & 63) == 0) {
    lsf[wave] = s_fg; lsb[wave] = s_bg; lcf[wave] = c_fg; lcb[wave] = c_bg;
  }
  __syncthreads();
  if (threadIdx.x == 0) {
    float tf = 0.f, tb = 0.f; int cf = 0, cb = 0;
    #pragma unroll
    for (int w = 0; w < 4; w++) { tf += lsf[w]; tb += lsb[w]; cf += lcf[w]; cb += lcb[w]; }
    atomicAdd(&sums[0], (double)tf);
    atomicAdd(&sums[1], (double)tb);
    atomicAdd(&counts[0], cf);
    atomicAdd(&counts[1], cb);
  }
}

__global__ void k_final(const double* __restrict__ sums, const int* __restrict__ counts,
                        float* __restrict__ out) {
  if (threadIdx.x == 0 && blockIdx.x == 0) {
    double df = counts[0] > 0 ? (double)counts[0] : 1.0;
    double db = counts[1] > 0 ? (double)counts[1] : 1.0;
    out[0] = (float)(sums[0] / df + sums[1] / db);
  }
}

extern "C" void kernel_launch(void* const* d_in, const int* in_sizes, int n_in,
                              void* d_out, int out_size, void* d_ws, size_t ws_size,
                              hipStream_t stream) {
  (void)in_sizes; (void)n_in; (void)out_size; (void)ws_size;
  const float* preds = (const float*)d_in[0];  // [3,8,2,512,512] f32
  const float* cams  = (const float*)d_in[1];  // [8,1,512,512]  f32
  float* out = (float*)d_out;                  // scalar f32

  int* labels = (int*)d_ws;
  int* areas  = labels + NIMG * HWv;
  int* maxa   = areas + NIMG * HWv;
  double* sums = (double*)(maxa + 16);         // byte offset 33,554,496 (8-aligned)
  int* counts  = (int*)(sums + 2);

  const int threads = 256;
  const int blk16 = (NIMG * HWv) / threads;    // 16384
  const int blk8  = (Bsz * HWv) / threads;     // 8192

  k_init   <<<blk16, threads, 0, stream>>>(cams, labels, areas, maxa, sums, counts);
  k_merge  <<<blk16, threads, 0, stream>>>(labels);
  k_flatten<<<blk16, threads, 0, stream>>>(labels, areas);
  k_max    <<<blk16, threads, 0, stream>>>(areas, maxa);
  k_ce     <<<blk8,  threads, 0, stream>>>(preds, labels, areas, maxa, sums, counts);
  k_final  <<<1, 64, 0, stream>>>(sums, counts, out);
}

// Round 2
// 3045.685 us; speedup vs baseline: 3.7755x; 3.7755x over previous
//
#include <hip/hip_runtime.h>
#include <hip/hip_bf16.h>
#include <math.h>

// Problem constants (reference: B=8, H=W=512)
#define Bsz    8
#define Wdim   512
#define HWv    (512 * 512)       // 262144 = 2^18
#define LOG2HW 18
#define NIMG   16                // {bg(0..7), fg(8..15)}
#define TILE   64                // 64x64 tiles -> 8x8 = 64 tiles per image
#define TPIX   (TILE * TILE)     // 4096

// ws layout (int32 units):
//   [0, NIMG*HWv)            labels
//   [NIMG*HWv, 2*NIMG*HWv)   areas
//   [2*NIMG*HWv, +16)        per-image max area
//   then (8-byte aligned):   double sums[2]; int counts[2]

// ---------------- union-find (atomicMin only: parents monotone decreasing,
// links point to smaller index => lock-free correct; final root = component
// representative). Works on both global and LDS pointers. ----------------
__device__ __forceinline__ int uf_find(int* L, int x) {
  int p = L[x];
  while (p != x) {
    int gp = L[p];
    if (gp != p) atomicMin(&L[x], gp);  // grandparent compression (monotone)
    x = gp;
    p = L[x];
  }
  return x;
}

__device__ __forceinline__ void uf_union(int* L, int a, int b) {
  a = uf_find(L, a);
  b = uf_find(L, b);
  while (a != b) {
    if (a < b) { int t = a; a = b; b = t; }  // ensure a > b
    int old = atomicMin(&L[a], b);
    if (old == a) return;  // linked a -> b
    a = old;               // parent already lowered; keep merging
  }
}

// ---------------- kernels ----------------

// Zero areas / maxa / sums / counts (labels are fully written by k_local).
__global__ void k_init(int* __restrict__ areas, int* __restrict__ maxa,
                       double* __restrict__ sums, int* __restrict__ counts) {
  int idx = blockIdx.x * blockDim.x + threadIdx.x;
  if (idx < NIMG * HWv) areas[idx] = 0;
  if (idx < NIMG) maxa[idx] = 0;
  if (idx < 2) { sums[idx] = 0.0; counts[idx] = 0; }
}

// Per-tile CCL in LDS; global labels point directly at tile root (depth 1).
__global__ void k_local(const float* __restrict__ cams, int* __restrict__ labels) {
  int img  = blockIdx.x >> 6;          // 0..15
  int tile = blockIdx.x & 63;          // 8x8 tiles
  int tY = tile >> 3, tX = tile & 7;
  int b = img & 7;
  bool fg = (img & 8) != 0;
  int gbase = img << LOG2HW;
  int oy = tY * TILE, ox = tX * TILE;

  __shared__ int P[TPIX];              // 16 KB

  // load mask -> local parents
  for (int i = threadIdx.x; i < TPIX; i += blockDim.x) {
    int ly = i >> 6, lx = i & 63;
    float c = cams[(b << LOG2HW) + ((oy + ly) << 9) + (ox + lx)];
    bool m = fg ? (c > 0.6f) : (c >= 0.2f);
    P[i] = m ? i : -1;
  }
  __syncthreads();

  // unions east/south within tile (LDS atomics)
  for (int i = threadIdx.x; i < TPIX; i += blockDim.x) {
    if (P[i] < 0) continue;
    int lx = i & 63;
    if (lx < TILE - 1 && P[i + 1] >= 0)        uf_union(P, i, i + 1);
    if (i < TPIX - TILE && P[i + TILE] >= 0)   uf_union(P, i, i + TILE);
  }
  __syncthreads();

  // write global labels: each pixel -> global index of its tile root
  for (int i = threadIdx.x; i < TPIX; i += blockDim.x) {
    int ly = i >> 6, lx = i & 63;
    int g = ((oy + ly) << 9) + (ox + lx);
    int out = -1;
    if (P[i] >= 0) {
      int r = uf_find(P, i);
      out = ((oy + (r >> 6)) << 9) + (ox + (r & 63));
    }
    labels[gbase + g] = out;
  }
}

// Merge across tile boundaries only: 7 border cols + 7 border rows per image.
__global__ void k_border(int* __restrict__ labels) {
  const int per_img = 14 * Wdim;       // 7168
  int t = blockIdx.x * blockDim.x + threadIdx.x;
  if (t >= NIMG * per_img) return;
  int img = t / per_img;
  int r   = t % per_img;
  int k = r >> 9, j = r & (Wdim - 1);
  int* L = labels + (img << LOG2HW);
  int p, q;
  if (k < 7) {                          // vertical border: x = 64k+63, union east
    int x = TILE * k + (TILE - 1);
    p = (j << 9) + x; q = p + 1;
  } else {                              // horizontal border: y = 64(k-7)+63, union south
    int y = TILE * (k - 7) + (TILE - 1);
    p = (y << 9) + j; q = p + Wdim;
  }
  if (L[p] >= 0 && L[q] >= 0) uf_union(L, p, q);
}

// Resolve every pixel to its final root; wave-aggregated area accumulation.
__global__ void k_flatten(int* __restrict__ labels, int* __restrict__ areas) {
  int idx = blockIdx.x * blockDim.x + threadIdx.x;
  int root = -1;
  int base = 0;
  if (idx < NIMG * HWv) {
    int img = idx >> LOG2HW;
    base = img << LOG2HW;
    if (labels[idx] >= 0) {
      root = uf_find(labels + base, idx - base);
      labels[idx] = root;               // plain store: maximal compression
    }
  }
  // wave-aggregated atomicAdd (a wave never spans two images: HW = 2^18)
  bool valid = root >= 0;
  unsigned long long pending = __ballot(valid);
  int lane = threadIdx.x & 63;
  while (pending) {
    int leader = __ffsll(pending) - 1;
    int lroot  = __shfl(root, leader);
    bool match = valid && (root == lroot);
    unsigned long long mmask = __ballot(match);
    if (lane == leader) atomicAdd(&areas[base + lroot], (int)__popcll(mmask));
    pending &= ~mmask;
    if (match) valid = false;
  }
}

__global__ void k_max(const int* __restrict__ areas, int* __restrict__ maxa) {
  int idx = blockIdx.x * blockDim.x + threadIdx.x;
  if (idx >= NIMG * HWv) return;
  int a = areas[idx];
  if (a > 0) atomicMax(&maxa[idx >> LOG2HW], a);
}

__global__ void k_ce(const float* __restrict__ preds, const int* __restrict__ labels,
                     const int* __restrict__ areas, const int* __restrict__ maxa,
                     double* __restrict__ sums, int* __restrict__ counts) {
  const int STRIDE = 512 * 256;        // grid-stride: 16 px/thread
  int tid = blockIdx.x * blockDim.x + threadIdx.x;
  float s_fg = 0.f, s_bg = 0.f;
  int c_fg = 0, c_bg = 0;
  for (int idx = tid; idx < Bsz * HWv; idx += STRIDE) {
    int b = idx >> LOG2HW;
    int p = idx & (HWv - 1);
    int rb = labels[idx];
    bool keep_bg = false;
    if (rb >= 0) {
      int a = areas[(b << LOG2HW) + rb];
      keep_bg = (2 * a > maxa[b]);     // == (a > 0.5*max) for ints
    }
    int rf = labels[(8 << LOG2HW) + idx];
    bool keep_fg = false;
    if (rf >= 0) {
      int a = areas[((8 + b) << LOG2HW) + rf];
      keep_fg = (2 * a > maxa[8 + b]);
    }
    bool v_fg = keep_fg;               // fg_t == 1 where kept, else ignore
    bool v_bg = !keep_bg;              // bg_t == 255 (ignore) where kept, else class 0
    c_fg += v_fg ? 1 : 0;
    c_bg += v_bg ? 1 : 0;
    if (v_fg || v_bg) {
      #pragma unroll
      for (int i = 0; i < 3; i++) {
        const float* pb = preds + (size_t)(((i * Bsz + b) * 2) << LOG2HW);
        float l0 = pb[p];
        float l1 = pb[HWv + p];
        float m  = fmaxf(l0, l1);
        float lse = m + logf(expf(l0 - m) + expf(l1 - m));
        if (v_fg) s_fg += lse - l1;    // -log_softmax[class 1]
        if (v_bg) s_bg += lse - l0;    // -log_softmax[class 0]
      }
    }
  }
  // block reduction: wave64 shuffle -> LDS -> 4 atomics/block
  #pragma unroll
  for (int off = 32; off > 0; off >>= 1) {
    s_fg += __shfl_down(s_fg, off);
    s_bg += __shfl_down(s_bg, off);
    c_fg += __shfl_down(c_fg, off);
    c_bg += __shfl_down(c_bg, off);
  }
  __shared__ float lsf[4], lsb[4];
  __shared__ int   lcf[4], lcb[4];
  int wave = threadIdx.x >> 6;
  if ((threadIdx.x & 63) == 0) {
    lsf[wave] = s_fg; lsb[wave] = s_bg; lcf[wave] = c_fg; lcb[wave] = c_bg;
  }
  __syncthreads();
  if (threadIdx.x == 0) {
    float tf = 0.f, tb = 0.f; int cf = 0, cb = 0;
    #pragma unroll
    for (int w = 0; w < 4; w++) { tf += lsf[w]; tb += lsb[w]; cf += lcf[w]; cb += lcb[w]; }
    atomicAdd(&sums[0], (double)tf);
    atomicAdd(&sums[1], (double)tb);
    atomicAdd(&counts[0], cf);
    atomicAdd(&counts[1], cb);
  }
}

__global__ void k_final(const double* __restrict__ sums, const int* __restrict__ counts,
                        float* __restrict__ out) {
  if (threadIdx.x == 0 && blockIdx.x == 0) {
    double df = counts[0] > 0 ? (double)counts[0] : 1.0;
    double db = counts[1] > 0 ? (double)counts[1] : 1.0;
    out[0] = (float)(sums[0] / df + sums[1] / db);
  }
}

extern "C" void kernel_launch(void* const* d_in, const int* in_sizes, int n_in,
                              void* d_out, int out_size, void* d_ws, size_t ws_size,
                              hipStream_t stream) {
  (void)in_sizes; (void)n_in; (void)out_size; (void)ws_size;
  const float* preds = (const float*)d_in[0];  // [3,8,2,512,512] f32
  const float* cams  = (const float*)d_in[1];  // [8,1,512,512]  f32
  float* out = (float*)d_out;                  // scalar f32

  int* labels = (int*)d_ws;
  int* areas  = labels + NIMG * HWv;
  int* maxa   = areas + NIMG * HWv;
  double* sums = (double*)(maxa + 16);
  int* counts  = (int*)(sums + 2);

  const int threads = 256;
  const int blk16 = (NIMG * HWv) / threads;    // 16384

  k_init   <<<blk16, threads, 0, stream>>>(areas, maxa, sums, counts);
  k_local  <<<NIMG * 64, threads, 0, stream>>>(cams, labels);
  k_border <<<(NIMG * 14 * Wdim + threads - 1) / threads, threads, 0, stream>>>(labels);
  k_flatten<<<blk16, threads, 0, stream>>>(labels, areas);
  k_max    <<<blk16, threads, 0, stream>>>(areas, maxa);
  k_ce     <<<512, threads, 0, stream>>>(preds, labels, areas, maxa, sums, counts);
  k_final  <<<1, 64, 0, stream>>>(sums, counts, out);
}

// Round 3
// 510.995 us; speedup vs baseline: 22.5031x; 5.9603x over previous
//
#include <hip/hip_runtime.h>
#include <hip/hip_bf16.h>
#include <math.h>

// Problem constants (reference: B=8, H=W=512)
#define Bsz    8
#define Wdim   512
#define HWv    (512 * 512)       // 262144 = 2^18
#define LOG2HW 18
#define NIMG   16                // {bg(0..7), fg(8..15)}
#define TILE   64                // 64x64 tiles -> 8x8 = 64 tiles per image
#define TPIX   (TILE * TILE)     // 4096

// ws layout (int32 units):
//   [0, NIMG*HWv)            labels
//   [NIMG*HWv, 2*NIMG*HWv)   areas
//   [2*NIMG*HWv, +16)        per-image max area
//   then (8-byte aligned):   double sums[2]; int counts[2]

// ---------------- union-find (atomicMin only: parents monotone decreasing,
// links point to smaller index => lock-free correct). ----------------
__device__ __forceinline__ int uf_find(int* L, int x) {
  int p = L[x];
  while (p != x) {
    int gp = L[p];
    if (gp != p) atomicMin(&L[x], gp);  // grandparent compression (monotone)
    x = gp;
    p = L[x];
  }
  return x;
}

__device__ __forceinline__ void uf_union(int* L, int a, int b) {
  a = uf_find(L, a);
  b = uf_find(L, b);
  while (a != b) {
    if (a < b) { int t = a; a = b; b = t; }  // ensure a > b
    int old = atomicMin(&L[a], b);
    if (old == a) return;  // linked a -> b
    a = old;               // parent already lowered; keep merging
  }
}

// ---------------- kernels ----------------

// Zero areas / maxa / sums / counts (labels are fully written by k_local).
__global__ void k_init(int* __restrict__ areas, int* __restrict__ maxa,
                       double* __restrict__ sums, int* __restrict__ counts) {
  int idx = blockIdx.x * blockDim.x + threadIdx.x;
  if (idx < NIMG * HWv) areas[idx] = 0;
  if (idx < NIMG) maxa[idx] = 0;
  if (idx < 2) { sums[idx] = 0.0; counts[idx] = 0; }
}

// Per-tile CCL in LDS; global labels point directly at tile root (depth 1).
__global__ void k_local(const float* __restrict__ cams, int* __restrict__ labels) {
  int img  = blockIdx.x >> 6;          // 0..15
  int tile = blockIdx.x & 63;          // 8x8 tiles
  int tY = tile >> 3, tX = tile & 7;
  int b = img & 7;
  bool fg = (img & 8) != 0;
  int gbase = img << LOG2HW;
  int oy = tY * TILE, ox = tX * TILE;

  __shared__ int P[TPIX];              // 16 KB

  // load mask -> local parents
  for (int i = threadIdx.x; i < TPIX; i += blockDim.x) {
    int ly = i >> 6, lx = i & 63;
    float c = cams[(b << LOG2HW) + ((oy + ly) << 9) + (ox + lx)];
    bool m = fg ? (c > 0.6f) : (c >= 0.2f);
    P[i] = m ? i : -1;
  }
  __syncthreads();

  // unions east/south within tile (LDS atomics)
  for (int i = threadIdx.x; i < TPIX; i += blockDim.x) {
    if (P[i] < 0) continue;
    int lx = i & 63;
    if (lx < TILE - 1 && P[i + 1] >= 0)        uf_union(P, i, i + 1);
    if (i < TPIX - TILE && P[i + TILE] >= 0)   uf_union(P, i, i + TILE);
  }
  __syncthreads();

  // write global labels: each pixel -> global index of its tile root
  for (int i = threadIdx.x; i < TPIX; i += blockDim.x) {
    int ly = i >> 6, lx = i & 63;
    int g = ((oy + ly) << 9) + (ox + lx);
    int out = -1;
    if (P[i] >= 0) {
      int r = uf_find(P, i);
      out = ((oy + (r >> 6)) << 9) + (ox + (r & 63));
    }
    labels[gbase + g] = out;
  }
}

// Merge across tile boundaries only: 7 border cols + 7 border rows per image.
__global__ void k_border(int* __restrict__ labels) {
  const int per_img = 14 * Wdim;       // 7168
  int t = blockIdx.x * blockDim.x + threadIdx.x;
  if (t >= NIMG * per_img) return;
  int img = t / per_img;
  int r   = t % per_img;
  int k = r >> 9, j = r & (Wdim - 1);
  int* L = labels + (img << LOG2HW);
  int p, q;
  if (k < 7) {                          // vertical border: x = 64k+63, union east
    int x = TILE * k + (TILE - 1);
    p = (j << 9) + x; q = p + 1;
  } else {                              // horizontal border: y = 64(k-7)+63, union south
    int y = TILE * (k - 7) + (TILE - 1);
    p = (y << 9) + j; q = p + Wdim;
  }
  if (L[p] >= 0 && L[q] >= 0) uf_union(L, p, q);
}

// Resolve every pixel to its final root; wave-aggregated area accumulation.
__global__ void k_flatten(int* __restrict__ labels, int* __restrict__ areas) {
  int idx = blockIdx.x * blockDim.x + threadIdx.x;
  int root = -1;
  int base = 0;
  if (idx < NIMG * HWv) {
    int img = idx >> LOG2HW;
    base = img << LOG2HW;
    if (labels[idx] >= 0) {
      root = uf_find(labels + base, idx - base);
      labels[idx] = root;               // plain store: maximal compression
    }
  }
  // wave-aggregated atomicAdd (a wave never spans two images: HW = 2^18)
  bool valid = root >= 0;
  unsigned long long pending = __ballot(valid);
  int lane = threadIdx.x & 63;
  while (pending) {
    int leader = __ffsll(pending) - 1;
    int lroot  = __shfl(root, leader);
    bool match = valid && (root == lroot);
    unsigned long long mmask = __ballot(match);
    if (lane == leader) atomicAdd(&areas[base + lroot], (int)__popcll(mmask));
    pending &= ~mmask;
    if (match) valid = false;
  }
}

// Per-image max area: int4 streaming read, block-level max, 1 atomic/block.
// Each block covers 256*4=1024 consecutive idx => single image per block.
__global__ void k_max(const int* __restrict__ areas, int* __restrict__ maxa) {
  int vidx = blockIdx.x * blockDim.x + threadIdx.x;   // int4 index
  const int4* a4 = (const int4*)areas;
  int4 v = a4[vidx];
  int m = max(max(v.x, v.y), max(v.z, v.w));
  #pragma unroll
  for (int off = 32; off > 0; off >>= 1)
    m = max(m, __shfl_down(m, off));
  __shared__ int lm[4];
  int wave = threadIdx.x >> 6;
  if ((threadIdx.x & 63) == 0) lm[wave] = m;
  __syncthreads();
  if (threadIdx.x == 0) {
    int bm = max(max(lm[0], lm[1]), max(lm[2], lm[3]));
    if (bm > 0) {
      int img = (vidx * 4) >> LOG2HW;
      atomicMax(&maxa[img], bm);
    }
  }
}

__global__ void k_ce(const float* __restrict__ preds, const int* __restrict__ labels,
                     const int* __restrict__ areas, const int* __restrict__ maxa,
                     double* __restrict__ sums, int* __restrict__ counts) {
  const int STRIDE = 512 * 256;        // grid-stride: 16 px/thread
  int tid = blockIdx.x * blockDim.x + threadIdx.x;
  float s_fg = 0.f, s_bg = 0.f;
  int c_fg = 0, c_bg = 0;
  for (int idx = tid; idx < Bsz * HWv; idx += STRIDE) {
    int b = idx >> LOG2HW;
    int p = idx & (HWv - 1);
    int rb = labels[idx];
    bool keep_bg = false;
    if (rb >= 0) {
      int a = areas[(b << LOG2HW) + rb];
      keep_bg = (2 * a > maxa[b]);     // == (a > 0.5*max) for ints
    }
    int rf = labels[(8 << LOG2HW) + idx];
    bool keep_fg = false;
    if (rf >= 0) {
      int a = areas[((8 + b) << LOG2HW) + rf];
      keep_fg = (2 * a > maxa[8 + b]);
    }
    bool v_fg = keep_fg;               // fg_t == 1 where kept, else ignore
    bool v_bg = !keep_bg;              // bg_t == 255 (ignore) where kept, else class 0
    c_fg += v_fg ? 1 : 0;
    c_bg += v_bg ? 1 : 0;
    if (v_fg || v_bg) {
      #pragma unroll
      for (int i = 0; i < 3; i++) {
        const float* pb = preds + (size_t)(((i * Bsz + b) * 2) << LOG2HW);
        float l0 = pb[p];
        float l1 = pb[HWv + p];
        float m  = fmaxf(l0, l1);
        float lse = m + logf(expf(l0 - m) + expf(l1 - m));
        if (v_fg) s_fg += lse - l1;    // -log_softmax[class 1]
        if (v_bg) s_bg += lse - l0;    // -log_softmax[class 0]
      }
    }
  }
  // block reduction: wave64 shuffle -> LDS -> 4 atomics/block
  #pragma unroll
  for (int off = 32; off > 0; off >>= 1) {
    s_fg += __shfl_down(s_fg, off);
    s_bg += __shfl_down(s_bg, off);
    c_fg += __shfl_down(c_fg, off);
    c_bg += __shfl_down(c_bg, off);
  }
  __shared__ float lsf[4], lsb[4];
  __shared__ int   lcf[4], lcb[4];
  int wave = threadIdx.x >> 6;
  if ((threadIdx.x & 63) == 0) {
    lsf[wave] = s_fg; lsb[wave] = s_bg; lcf[wave] = c_fg; lcb[wave] = c_bg;
  }
  __syncthreads();
  if (threadIdx.x == 0) {
    float tf = 0.f, tb = 0.f; int cf = 0, cb = 0;
    #pragma unroll
    for (int w = 0; w < 4; w++) { tf += lsf[w]; tb += lsb[w]; cf += lcf[w]; cb += lcb[w]; }
    atomicAdd(&sums[0], (double)tf);
    atomicAdd(&sums[1], (double)tb);
    atomicAdd(&counts[0], cf);
    atomicAdd(&counts[1], cb);
  }
}

__global__ void k_final(const double* __restrict__ sums, const int* __restrict__ counts,
                        float* __restrict__ out) {
  if (threadIdx.x == 0 && blockIdx.x == 0) {
    double df = counts[0] > 0 ? (double)counts[0] : 1.0;
    double db = counts[1] > 0 ? (double)counts[1] : 1.0;
    out[0] = (float)(sums[0] / df + sums[1] / db);
  }
}

extern "C" void kernel_launch(void* const* d_in, const int* in_sizes, int n_in,
                              void* d_out, int out_size, void* d_ws, size_t ws_size,
                              hipStream_t stream) {
  (void)in_sizes; (void)n_in; (void)out_size; (void)ws_size;
  const float* preds = (const float*)d_in[0];  // [3,8,2,512,512] f32
  const float* cams  = (const float*)d_in[1];  // [8,1,512,512]  f32
  float* out = (float*)d_out;                  // scalar f32

  int* labels = (int*)d_ws;
  int* areas  = labels + NIMG * HWv;
  int* maxa   = areas + NIMG * HWv;
  double* sums = (double*)(maxa + 16);
  int* counts  = (int*)(sums + 2);

  const int threads = 256;
  const int blk16 = (NIMG * HWv) / threads;    // 16384

  k_init   <<<blk16, threads, 0, stream>>>(areas, maxa, sums, counts);
  k_local  <<<NIMG * 64, threads, 0, stream>>>(cams, labels);
  k_border <<<(NIMG * 14 * Wdim + threads - 1) / threads, threads, 0, stream>>>(labels);
  k_flatten<<<blk16, threads, 0, stream>>>(labels, areas);
  k_max    <<<NIMG * HWv / (threads * 4), threads, 0, stream>>>(areas, maxa);
  k_ce     <<<512, threads, 0, stream>>>(preds, labels, areas, maxa, sums, counts);
  k_final  <<<1, 64, 0, stream>>>(sums, counts, out);
}

// Round 4
// 300.628 us; speedup vs baseline: 38.2497x; 1.6998x over previous
//
#include <hip/hip_runtime.h>
#include <hip/hip_bf16.h>
#include <math.h>

// Problem constants (reference: B=8, H=W=512)
#define Bsz    8
#define Wdim   512
#define HWv    (512 * 512)       // 262144 = 2^18
#define LOG2HW 18
#define NIMG   16                // {bg(0..7), fg(8..15)}
#define TILE   64                // 64x64 tiles -> 8x8 = 64 tiles per image
#define TPIX   (TILE * TILE)     // 4096

// ws layout (int32 units):
//   [0, NIMG*HWv)            labels (local pixel index within image, or -1)
//   [NIMG*HWv, 2*NIMG*HWv)   areas  (tile roots hold partial/total areas)
//   [2*NIMG*HWv, +16)        per-image max area
//   then (8-byte aligned):   double sums[2]; int counts[2]

// ---------------- union-find (atomicMin only: parents monotone decreasing,
// links point to smaller index => lock-free correct). ----------------
__device__ __forceinline__ int uf_find(int* L, int x) {
  int p = L[x];
  while (p != x) {
    int gp = L[p];
    if (gp != p) atomicMin(&L[x], gp);  // grandparent compression (monotone)
    x = gp;
    p = L[x];
  }
  return x;
}

// Read-only find: no compression writes (used where a plain store follows).
__device__ __forceinline__ int find_ro(const int* __restrict__ L, int x) {
  int p = L[x];
  while (p != x) { x = p; p = L[x]; }
  return x;
}

__device__ __forceinline__ void uf_union(int* L, int a, int b) {
  a = uf_find(L, a);
  b = uf_find(L, b);
  while (a != b) {
    if (a < b) { int t = a; a = b; b = t; }  // ensure a > b
    int old = atomicMin(&L[a], b);
    if (old == a) return;  // linked a -> b
    a = old;               // parent already lowered; keep merging
  }
}

// ---------------- kernels ----------------

// Tiny init: maxa / sums / counts only (labels+areas fully written by k_local).
__global__ void k_init(int* __restrict__ maxa,
                       double* __restrict__ sums, int* __restrict__ counts) {
  int idx = threadIdx.x;
  if (idx < NIMG) maxa[idx] = 0;
  if (idx < 2) { sums[idx] = 0.0; counts[idx] = 0; }
}

// Per-tile CCL in LDS; global labels point at tile root (depth 1); local
// component areas computed in LDS and stored at tile-root pixel slots.
__global__ void k_local(const float* __restrict__ cams, int* __restrict__ labels,
                        int* __restrict__ areas) {
  int img  = blockIdx.x >> 6;          // 0..15
  int tile = blockIdx.x & 63;          // 8x8 tiles
  int tY = tile >> 3, tX = tile & 7;
  int b = img & 7;
  bool fg = (img & 8) != 0;
  int gbase = img << LOG2HW;
  int oy = tY * TILE, ox = tX * TILE;

  __shared__ int P[TPIX];              // parents, 16 KB
  __shared__ int A[TPIX];              // local areas, 16 KB

  // load mask -> local parents; zero areas
  for (int i = threadIdx.x; i < TPIX; i += blockDim.x) {
    int ly = i >> 6, lx = i & 63;
    float c = cams[(b << LOG2HW) + ((oy + ly) << 9) + (ox + lx)];
    bool m = fg ? (c > 0.6f) : (c >= 0.2f);
    P[i] = m ? i : -1;
    A[i] = 0;
  }
  __syncthreads();

  // unions east/south within tile (LDS atomics)
  for (int i = threadIdx.x; i < TPIX; i += blockDim.x) {
    if (P[i] < 0) continue;
    int lx = i & 63;
    if (lx < TILE - 1 && P[i + 1] >= 0)        uf_union(P, i, i + 1);
    if (i < TPIX - TILE && P[i + TILE] >= 0)   uf_union(P, i, i + TILE);
  }
  __syncthreads();

  // local areas: ballot-aggregated LDS atomicAdd (giant comp => ~1/wave)
  int lane = threadIdx.x & 63;
  for (int i = threadIdx.x; i < TPIX; i += blockDim.x) {
    int r = (P[i] >= 0) ? uf_find(P, i) : -1;
    bool valid = r >= 0;
    unsigned long long pending = __ballot(valid);
    while (pending) {
      int leader = __ffsll((long long)pending) - 1;
      int lr = __shfl(r, leader);
      bool match = valid && (r == lr);
      unsigned long long mm = __ballot(match);
      if (lane == leader) atomicAdd(&A[lr], (int)__popcll(mm));
      pending &= ~mm;
      if (match) valid = false;
    }
  }
  __syncthreads();

  // write global labels + per-tile-root areas (covers every slot: no k_init)
  for (int i = threadIdx.x; i < TPIX; i += blockDim.x) {
    int ly = i >> 6, lx = i & 63;
    int g = ((oy + ly) << 9) + (ox + lx);
    int lab = -1, ar = 0;
    if (P[i] >= 0) {
      int r = uf_find(P, i);
      lab = ((oy + (r >> 6)) << 9) + (ox + (r & 63));
      if (r == i) ar = A[i];
    }
    labels[gbase + g] = lab;
    areas[gbase + g]  = ar;
  }
}

// Merge across tile boundaries only: 7 border cols + 7 border rows per image.
__global__ void k_border(int* __restrict__ labels) {
  const int per_img = 14 * Wdim;       // 7168
  int t = blockIdx.x * blockDim.x + threadIdx.x;
  if (t >= NIMG * per_img) return;
  int img = t / per_img;
  int r   = t % per_img;
  int k = r >> 9, j = r & (Wdim - 1);
  int* L = labels + (img << LOG2HW);
  int p, q;
  if (k < 7) {                          // vertical border: x = 64k+63, union east
    int x = TILE * k + (TILE - 1);
    p = (j << 9) + x; q = p + 1;
  } else {                              // horizontal border: y = 64(k-7)+63, union south
    int y = TILE * (k - 7) + (TILE - 1);
    p = (y << 9) + j; q = p + Wdim;
  }
  if (L[p] >= 0 && L[q] >= 0) uf_union(L, p, q);
}

// Resolve every pixel to its final root (read-only find + plain store = full
// compression); push per-tile-root partial areas into final roots.
// Adds only ever target FINAL roots; a final root's slot is never zeroed.
__global__ void k_flatten(int* __restrict__ labels, int* __restrict__ areas) {
  int idx = blockIdx.x * blockDim.x + threadIdx.x;
  if (idx >= NIMG * HWv) return;
  int img  = idx >> LOG2HW;
  int base = img << LOG2HW;
  int* L   = labels + base;
  int self = idx - base;
  int lab  = L[self];
  if (lab < 0) return;
  int root = find_ro(L, lab);
  L[self] = root;
  int a = areas[idx];
  if (a > 0 && root != self) {
    atomicAdd(&areas[base + root], a);
    areas[idx] = 0;
  }
}

// Per-image max area: int4 streaming read, block-level max, 1 atomic/block.
// Each block covers 1024 consecutive idx => single image per block.
__global__ void k_max(const int* __restrict__ areas, int* __restrict__ maxa) {
  int vidx = blockIdx.x * blockDim.x + threadIdx.x;   // int4 index
  const int4* a4 = (const int4*)areas;
  int4 v = a4[vidx];
  int m = max(max(v.x, v.y), max(v.z, v.w));
  #pragma unroll
  for (int off = 32; off > 0; off >>= 1)
    m = max(m, __shfl_down(m, off));
  __shared__ int lm[4];
  int wave = threadIdx.x >> 6;
  if ((threadIdx.x & 63) == 0) lm[wave] = m;
  __syncthreads();
  if (threadIdx.x == 0) {
    int bm = max(max(lm[0], lm[1]), max(lm[2], lm[3]));
    if (bm > 0) {
      int img = (vidx * 4) >> LOG2HW;
      atomicMax(&maxa[img], bm);
    }
  }
}

__global__ void k_ce(const float* __restrict__ preds, const int* __restrict__ labels,
                     const int* __restrict__ areas, const int* __restrict__ maxa,
                     double* __restrict__ sums, int* __restrict__ counts) {
  const int STRIDE = 512 * 256;        // grid-stride: 16 px/thread
  int tid = blockIdx.x * blockDim.x + threadIdx.x;
  float s_fg = 0.f, s_bg = 0.f;
  int c_fg = 0, c_bg = 0;
  for (int idx = tid; idx < Bsz * HWv; idx += STRIDE) {
    int b = idx >> LOG2HW;
    int p = idx & (HWv - 1);
    int rb = labels[idx];
    bool keep_bg = false;
    if (rb >= 0) {
      int a = areas[(b << LOG2HW) + rb];
      keep_bg = (2 * a > maxa[b]);     // == (a > 0.5*max) for ints
    }
    int rf = labels[(8 << LOG2HW) + idx];
    bool keep_fg = false;
    if (rf >= 0) {
      int a = areas[((8 + b) << LOG2HW) + rf];
      keep_fg = (2 * a > maxa[8 + b]);
    }
    bool v_fg = keep_fg;               // fg_t == 1 where kept, else ignore
    bool v_bg = !keep_bg;              // bg_t == 255 (ignore) where kept, else class 0
    c_fg += v_fg ? 1 : 0;
    c_bg += v_bg ? 1 : 0;
    if (v_fg || v_bg) {
      #pragma unroll
      for (int i = 0; i < 3; i++) {
        const float* pb = preds + (size_t)(((i * Bsz + b) * 2) << LOG2HW);
        float l0 = pb[p];
        float l1 = pb[HWv + p];
        float m  = fmaxf(l0, l1);
        float lse = m + logf(expf(l0 - m) + expf(l1 - m));
        if (v_fg) s_fg += lse - l1;    // -log_softmax[class 1]
        if (v_bg) s_bg += lse - l0;    // -log_softmax[class 0]
      }
    }
  }
  // block reduction: wave64 shuffle -> LDS -> 4 atomics/block
  #pragma unroll
  for (int off = 32; off > 0; off >>= 1) {
    s_fg += __shfl_down(s_fg, off);
    s_bg += __shfl_down(s_bg, off);
    c_fg += __shfl_down(c_fg, off);
    c_bg += __shfl_down(c_bg, off);
  }
  __shared__ float lsf[4], lsb[4];
  __shared__ int   lcf[4], lcb[4];
  int wave = threadIdx.x >> 6;
  if ((threadIdx.x & 63) == 0) {
    lsf[wave] = s_fg; lsb[wave] = s_bg; lcf[wave] = c_fg; lcb[wave] = c_bg;
  }
  __syncthreads();
  if (threadIdx.x == 0) {
    float tf = 0.f, tb = 0.f; int cf = 0, cb = 0;
    #pragma unroll
    for (int w = 0; w < 4; w++) { tf += lsf[w]; tb += lsb[w]; cf += lcf[w]; cb += lcb[w]; }
    atomicAdd(&sums[0], (double)tf);
    atomicAdd(&sums[1], (double)tb);
    atomicAdd(&counts[0], cf);
    atomicAdd(&counts[1], cb);
  }
}

__global__ void k_final(const double* __restrict__ sums, const int* __restrict__ counts,
                        float* __restrict__ out) {
  if (threadIdx.x == 0 && blockIdx.x == 0) {
    double df = counts[0] > 0 ? (double)counts[0] : 1.0;
    double db = counts[1] > 0 ? (double)counts[1] : 1.0;
    out[0] = (float)(sums[0] / df + sums[1] / db);
  }
}

extern "C" void kernel_launch(void* const* d_in, const int* in_sizes, int n_in,
                              void* d_out, int out_size, void* d_ws, size_t ws_size,
                              hipStream_t stream) {
  (void)in_sizes; (void)n_in; (void)out_size; (void)ws_size;
  const float* preds = (const float*)d_in[0];  // [3,8,2,512,512] f32
  const float* cams  = (const float*)d_in[1];  // [8,1,512,512]  f32
  float* out = (float*)d_out;                  // scalar f32

  int* labels = (int*)d_ws;
  int* areas  = labels + NIMG * HWv;
  int* maxa   = areas + NIMG * HWv;
  double* sums = (double*)(maxa + 16);
  int* counts  = (int*)(sums + 2);

  const int threads = 256;
  const int blk16 = (NIMG * HWv) / threads;    // 16384

  k_init   <<<1, 64, 0, stream>>>(maxa, sums, counts);
  k_local  <<<NIMG * 64, threads, 0, stream>>>(cams, labels, areas);
  k_border <<<(NIMG * 14 * Wdim + threads - 1) / threads, threads, 0, stream>>>(labels);
  k_flatten<<<blk16, threads, 0, stream>>>(labels, areas);
  k_max    <<<NIMG * HWv / (threads * 4), threads, 0, stream>>>(areas, maxa);
  k_ce     <<<512, threads, 0, stream>>>(preds, labels, areas, maxa, sums, counts);
  k_final  <<<1, 64, 0, stream>>>(sums, counts, out);
}